// Round 2
// baseline (12647.540 us; speedup 1.0000x reference)
//
#include <hip/hip_runtime.h>

#define S_ELE (256 * 1024)   // one [B=256, H=1024] plane (floats)

__device__ __forceinline__ float clip01(float b) { return fminf(fmaxf(b, 0.0f), 1.0f); }

// 64x64 tile of C = A(64xK) * B^T(64xK). 64 threads, 8x8/thread. K = KCH*16.
// k-major LDS (As[k][m]), 16-k chunks, double-buffered, register prefetch.
// Per-output-element accumulation is strictly sequential in k.
template <int KCH>
__device__ __forceinline__ void gemm64(const float* __restrict__ A, long lda,
                                       const float* __restrict__ B, long ldb,
                                       float* __restrict__ Pout, int tm, int tn)
{
    __shared__ float As[2][16][68];
    __shared__ float Bs[2][16][68];

    const int lane = threadIdx.x;
    const int sr = lane >> 2;          // staging row 0..15
    const int sk = (lane & 3) << 2;    // staging k 0,4,8,12
    const int r0 = (lane >> 3) << 3;   // 8-row group
    const int cq = (lane & 7) << 2;    // 4-col group (+32 for second half)

    const float* Ab = A + (size_t)(tm * 64) * lda;
    const float* Bb = B + (size_t)(tn * 64) * ldb;

    float4 pa[4], pb[4];
    #pragma unroll
    for (int p = 0; p < 4; ++p) {
        pa[p] = *reinterpret_cast<const float4*>(&Ab[(size_t)(sr + 16 * p) * lda + sk]);
        pb[p] = *reinterpret_cast<const float4*>(&Bb[(size_t)(sr + 16 * p) * ldb + sk]);
    }

    float acc[8][8] = {};

    #pragma unroll 2
    for (int c = 0; c < KCH; ++c) {
        const int buf = c & 1;
        #pragma unroll
        for (int p = 0; p < 4; ++p) {
            const int m = sr + 16 * p;
            As[buf][sk + 0][m] = pa[p].x; As[buf][sk + 1][m] = pa[p].y;
            As[buf][sk + 2][m] = pa[p].z; As[buf][sk + 3][m] = pa[p].w;
            Bs[buf][sk + 0][m] = pb[p].x; Bs[buf][sk + 1][m] = pb[p].y;
            Bs[buf][sk + 2][m] = pb[p].z; Bs[buf][sk + 3][m] = pb[p].w;
        }
        __syncthreads();
        if (c + 1 < KCH) {
            const int ko = (c + 1) * 16;
            #pragma unroll
            for (int p = 0; p < 4; ++p) {
                pa[p] = *reinterpret_cast<const float4*>(&Ab[(size_t)(sr + 16 * p) * lda + ko + sk]);
                pb[p] = *reinterpret_cast<const float4*>(&Bb[(size_t)(sr + 16 * p) * ldb + ko + sk]);
            }
        }
        #pragma unroll
        for (int k = 0; k < 16; ++k) {
            float4 a0 = *reinterpret_cast<const float4*>(&As[buf][k][r0]);
            float4 a1 = *reinterpret_cast<const float4*>(&As[buf][k][r0 + 4]);
            float4 b0 = *reinterpret_cast<const float4*>(&Bs[buf][k][cq]);
            float4 b1 = *reinterpret_cast<const float4*>(&Bs[buf][k][cq + 32]);
            float a[8] = {a0.x, a0.y, a0.z, a0.w, a1.x, a1.y, a1.z, a1.w};
            float b[8] = {b0.x, b0.y, b0.z, b0.w, b1.x, b1.y, b1.z, b1.w};
            #pragma unroll
            for (int i = 0; i < 8; ++i)
                #pragma unroll
                for (int j = 0; j < 8; ++j)
                    acc[i][j] = fmaf(a[i], b[j], acc[i][j]);
        }
        __syncthreads();
    }

    #pragma unroll
    for (int i = 0; i < 8; ++i) {
        float4 v0 = make_float4(acc[i][0], acc[i][1], acc[i][2], acc[i][3]);
        float4 v1 = make_float4(acc[i][4], acc[i][5], acc[i][6], acc[i][7]);
        float* row = Pout + (size_t)(tm * 64 + r0 + i) * 1024 + tn * 64;
        *reinterpret_cast<float4*>(&row[cq])      = v0;
        *reinterpret_cast<float4*>(&row[cq + 32]) = v1;
    }
}

// 32x64 tile variant: 64 threads, 4x8/thread. Same sequential-k numerics.
template <int KCH>
__device__ __forceinline__ void gemm32(const float* __restrict__ A, long lda,
                                       const float* __restrict__ B, long ldb,
                                       float* __restrict__ Pout, int tm, int tn)
{
    __shared__ float As[2][16][36];
    __shared__ float Bs[2][16][68];

    const int lane = threadIdx.x;
    const int sr = lane >> 2;          // 0..15
    const int sk = (lane & 3) << 2;    // 0,4,8,12
    const int r0 = (lane >> 3) << 2;   // 4-row group within 32
    const int cq = (lane & 7) << 2;

    const float* Ab = A + (size_t)(tm * 32) * lda;
    const float* Bb = B + (size_t)(tn * 64) * ldb;

    float4 pa[2], pb[4];
    #pragma unroll
    for (int p = 0; p < 2; ++p)
        pa[p] = *reinterpret_cast<const float4*>(&Ab[(size_t)(sr + 16 * p) * lda + sk]);
    #pragma unroll
    for (int p = 0; p < 4; ++p)
        pb[p] = *reinterpret_cast<const float4*>(&Bb[(size_t)(sr + 16 * p) * ldb + sk]);

    float acc[4][8] = {};

    #pragma unroll 2
    for (int c = 0; c < KCH; ++c) {
        const int buf = c & 1;
        #pragma unroll
        for (int p = 0; p < 2; ++p) {
            const int m = sr + 16 * p;
            As[buf][sk + 0][m] = pa[p].x; As[buf][sk + 1][m] = pa[p].y;
            As[buf][sk + 2][m] = pa[p].z; As[buf][sk + 3][m] = pa[p].w;
        }
        #pragma unroll
        for (int p = 0; p < 4; ++p) {
            const int m = sr + 16 * p;
            Bs[buf][sk + 0][m] = pb[p].x; Bs[buf][sk + 1][m] = pb[p].y;
            Bs[buf][sk + 2][m] = pb[p].z; Bs[buf][sk + 3][m] = pb[p].w;
        }
        __syncthreads();
        if (c + 1 < KCH) {
            const int ko = (c + 1) * 16;
            #pragma unroll
            for (int p = 0; p < 2; ++p)
                pa[p] = *reinterpret_cast<const float4*>(&Ab[(size_t)(sr + 16 * p) * lda + ko + sk]);
            #pragma unroll
            for (int p = 0; p < 4; ++p)
                pb[p] = *reinterpret_cast<const float4*>(&Bb[(size_t)(sr + 16 * p) * ldb + ko + sk]);
        }
        #pragma unroll
        for (int k = 0; k < 16; ++k) {
            float4 a0 = *reinterpret_cast<const float4*>(&As[buf][k][r0]);
            float4 b0 = *reinterpret_cast<const float4*>(&Bs[buf][k][cq]);
            float4 b1 = *reinterpret_cast<const float4*>(&Bs[buf][k][cq + 32]);
            float a[4] = {a0.x, a0.y, a0.z, a0.w};
            float b[8] = {b0.x, b0.y, b0.z, b0.w, b1.x, b1.y, b1.z, b1.w};
            #pragma unroll
            for (int i = 0; i < 4; ++i)
                #pragma unroll
                for (int j = 0; j < 8; ++j)
                    acc[i][j] = fmaf(a[i], b[j], acc[i][j]);
        }
        __syncthreads();
    }

    #pragma unroll
    for (int i = 0; i < 4; ++i) {
        float4 v0 = make_float4(acc[i][0], acc[i][1], acc[i][2], acc[i][3]);
        float4 v1 = make_float4(acc[i][4], acc[i][5], acc[i][6], acc[i][7]);
        float* row = Pout + (size_t)(tm * 32 + r0 + i) * 1024 + tn * 64;
        *reinterpret_cast<float4*>(&row[cq])      = v0;
        *reinterpret_cast<float4*>(&row[cq + 32]) = v1;
    }
}

// spk1 @ W1r^T, 8-way split-K (K=128 each). grid = (64 tiles, 8 splits)
__global__ __launch_bounds__(64, 2) void l1_gemm(const float* __restrict__ spk1,
    const float* __restrict__ W1r, float* __restrict__ P)
{
    const int split = blockIdx.y;
    const long koff = (long)split * 128;
    gemm64<8>(spk1 + koff, 1024, W1r + koff, 1024,
              P + (size_t)split * S_ELE, blockIdx.x & 3, blockIdx.x >> 2);
}

// layer-2: [spk1@W2^T | spk2@W2r^T], 2 splits of K=512 each (round-0 boundaries).
// grid = (128 tiles of 32x64, 2 splits, 2 pairs)
__global__ __launch_bounds__(64, 2) void l2_gemm(const float* __restrict__ spk1,
    const float* __restrict__ spk2, const float* __restrict__ W2,
    const float* __restrict__ W2r, float* __restrict__ P)
{
    const int split = blockIdx.y, pair = blockIdx.z;
    const float* A = pair ? spk2 : spk1;
    const float* B = pair ? W2r  : W2;
    const long koff = (long)split * 512;
    gemm32<32>(A + koff, 1024, B + koff, 1024,
               P + (size_t)(pair * 2 + split) * S_ELE, blockIdx.x & 7, blockIdx.x >> 3);
}

// Hoisted x @ W1^T for a chunk of timesteps. grid = (64 tiles, T_CH)
__global__ __launch_bounds__(64, 2) void xw1_gemm(const float* __restrict__ x0,
    const float* __restrict__ W1, float* __restrict__ out)
{
    const int t = blockIdx.y;
    gemm64<32>(x0 + (size_t)t * 512, 51200, W1, 512,
               out + (size_t)t * S_ELE, blockIdx.x & 3, blockIdx.x >> 2);
}

// cur = xw1_t + P0 + ... + P7 (sequential, round-1 validated order)
__global__ __launch_bounds__(256) void update_l1(const float* __restrict__ P,
    const float* __restrict__ xw, const float* __restrict__ betap,
    float* __restrict__ mem, float* __restrict__ spk, float* __restrict__ spk_rec)
{
    const int i = (blockIdx.x * 256 + threadIdx.x) * 4;
    const float b = clip01(*betap);
    float4 cur = *reinterpret_cast<const float4*>(&xw[i]);
    #pragma unroll
    for (int sp = 0; sp < 8; ++sp) {
        float4 p = *reinterpret_cast<const float4*>(&P[(size_t)sp * S_ELE + i]);
        cur.x += p.x; cur.y += p.y; cur.z += p.z; cur.w += p.w;
    }
    float4 mo = *reinterpret_cast<const float4*>(&mem[i]);
    float4 mn, s;
    mn.x = b * mo.x + cur.x - (mo.x > 1.0f ? 1.0f : 0.0f); s.x = (mn.x - 1.0f) > 0.0f ? 1.0f : 0.0f;
    mn.y = b * mo.y + cur.y - (mo.y > 1.0f ? 1.0f : 0.0f); s.y = (mn.y - 1.0f) > 0.0f ? 1.0f : 0.0f;
    mn.z = b * mo.z + cur.z - (mo.z > 1.0f ? 1.0f : 0.0f); s.z = (mn.z - 1.0f) > 0.0f ? 1.0f : 0.0f;
    mn.w = b * mo.w + cur.w - (mo.w > 1.0f ? 1.0f : 0.0f); s.w = (mn.w - 1.0f) > 0.0f ? 1.0f : 0.0f;
    *reinterpret_cast<float4*>(&mem[i])     = mn;
    *reinterpret_cast<float4*>(&spk[i])     = s;
    *reinterpret_cast<float4*>(&spk_rec[i]) = s;
}

// cur2 = (P0 + P1) + (P2 + P3)  -- round-0 bitwise order; fused readout.
__global__ __launch_bounds__(256) void update_l2_ro(const float* __restrict__ P,
    const float* __restrict__ betap, const float* __restrict__ bop,
    float* __restrict__ mem, float* __restrict__ spk2,
    const float* __restrict__ Wout, float* __restrict__ memo, float* __restrict__ rec)
{
    __shared__ float s_spk[1024];
    const int bb = blockIdx.x;
    const int h4 = threadIdx.x * 4;
    const size_t base = (size_t)bb * 1024 + h4;
    const float b = clip01(*betap);

    float4 p0 = *reinterpret_cast<const float4*>(&P[base]);
    float4 p1 = *reinterpret_cast<const float4*>(&P[(size_t)S_ELE + base]);
    float4 p2 = *reinterpret_cast<const float4*>(&P[(size_t)2 * S_ELE + base]);
    float4 p3 = *reinterpret_cast<const float4*>(&P[(size_t)3 * S_ELE + base]);
    float4 cur;
    cur.x = (p0.x + p1.x) + (p2.x + p3.x);
    cur.y = (p0.y + p1.y) + (p2.y + p3.y);
    cur.z = (p0.z + p1.z) + (p2.z + p3.z);
    cur.w = (p0.w + p1.w) + (p2.w + p3.w);

    float4 mo = *reinterpret_cast<const float4*>(&mem[base]);
    float4 mn, s;
    mn.x = b * mo.x + cur.x - (mo.x > 1.0f ? 1.0f : 0.0f); s.x = (mn.x - 1.0f) > 0.0f ? 1.0f : 0.0f;
    mn.y = b * mo.y + cur.y - (mo.y > 1.0f ? 1.0f : 0.0f); s.y = (mn.y - 1.0f) > 0.0f ? 1.0f : 0.0f;
    mn.z = b * mo.z + cur.z - (mo.z > 1.0f ? 1.0f : 0.0f); s.z = (mn.z - 1.0f) > 0.0f ? 1.0f : 0.0f;
    mn.w = b * mo.w + cur.w - (mo.w > 1.0f ? 1.0f : 0.0f); s.w = (mn.w - 1.0f) > 0.0f ? 1.0f : 0.0f;
    *reinterpret_cast<float4*>(&mem[base])  = mn;
    *reinterpret_cast<float4*>(&spk2[base]) = s;
    *reinterpret_cast<float4*>(&s_spk[h4])  = s;
    __syncthreads();

    const int wave = threadIdx.x >> 6, lane = threadIdx.x & 63;
    const float bo = clip01(*bop);
    for (int o = wave; o < 10; o += 4) {
        float sum = 0.0f;
        #pragma unroll
        for (int i = 0; i < 16; ++i)
            sum = fmaf(s_spk[lane + 64 * i], Wout[o * 1024 + lane + 64 * i], sum);
        #pragma unroll
        for (int off = 32; off > 0; off >>= 1) sum += __shfl_down(sum, off);
        if (lane == 0) {
            const float m = bo * memo[bb * 10 + o] + sum;
            memo[bb * 10 + o] = m;
            rec[bb * 10 + o] = m;
        }
    }
}

extern "C" void kernel_launch(void* const* d_in, const int* in_sizes, int n_in,
                              void* d_out, int out_size, void* d_ws, size_t ws_size,
                              hipStream_t stream)
{
    const float* x    = (const float*)d_in[0];   // [256,100,512]
    const float* W1   = (const float*)d_in[1];   // [1024,512]
    const float* W1r  = (const float*)d_in[2];   // [1024,1024]
    const float* W2   = (const float*)d_in[3];   // [1024,1024]
    const float* W2r  = (const float*)d_in[4];   // [1024,1024]
    const float* Wout = (const float*)d_in[5];   // [10,1024]
    const float* b1   = (const float*)d_in[6];
    const float* b2   = (const float*)d_in[7];
    const float* bo   = (const float*)d_in[8];

    float* out      = (float*)d_out;
    float* spk1_rec = out;                         // [100,256,1024]
    float* mout_rec = out + (size_t)100 * S_ELE;   // [100,256,10]

    float* w = (float*)d_ws;
    float* mem1 = w;  w += S_ELE;
    float* mem2 = w;  w += S_ELE;
    float* spk1 = w;  w += S_ELE;
    float* spk2 = w;  w += S_ELE;
    float* P1   = w;  w += 8 * S_ELE;    // layer-1 recurrent split partials
    float* P2   = w;  w += 4 * S_ELE;    // layer-2: W2 lo/hi, W2r lo/hi
    float* memo = w;  w += 2560;
    float* xw1  = w;                     // hoisted x@W1^T chunk buffer

    const size_t used = (size_t)(w - (float*)d_ws) * sizeof(float);
    int T_CH = 1;
    const int cands[] = {100, 50, 25, 20, 10, 5, 4, 2, 1};   // divisors of 100
    for (int c : cands)
        if (used + (size_t)c * S_ELE * sizeof(float) <= ws_size) { T_CH = c; break; }

    hipMemsetAsync(mem1, 0, (size_t)S_ELE * 4, stream);
    hipMemsetAsync(mem2, 0, (size_t)S_ELE * 4, stream);
    hipMemsetAsync(spk1, 0, (size_t)S_ELE * 4, stream);
    hipMemsetAsync(spk2, 0, (size_t)S_ELE * 4, stream);
    hipMemsetAsync(memo, 0, 2560 * 4, stream);

    for (int t = 0; t < 100; ++t) {
        if (t % T_CH == 0)
            hipLaunchKernelGGL(xw1_gemm, dim3(64, T_CH), dim3(64), 0, stream,
                               x + (size_t)t * 512, W1, xw1);

        hipLaunchKernelGGL(l1_gemm, dim3(64, 8), dim3(64), 0, stream, spk1, W1r, P1);

        hipLaunchKernelGGL(update_l1, dim3(256), dim3(256), 0, stream,
                           P1, xw1 + (size_t)(t % T_CH) * S_ELE, b1,
                           mem1, spk1, spk1_rec + (size_t)t * S_ELE);

        hipLaunchKernelGGL(l2_gemm, dim3(128, 2, 2), dim3(64), 0, stream,
                           spk1, spk2, W2, W2r, P2);

        hipLaunchKernelGGL(update_l2_ro, dim3(256), dim3(256), 0, stream,
                           P2, b2, bo, mem2, spk2, Wout, memo,
                           mout_rec + (size_t)t * 2560);
    }
}